// Round 6
// baseline (280.224 us; speedup 1.0000x reference)
//
#include <hip/hip_runtime.h>
#include <hip/hip_bf16.h>
#include <stdint.h>

#define SEGN 8
#define LSEG 1024
#define SS   8192
#define EE   1152
#define HH   16
#define DD   72
#define DP   96
#define E3   3456
#define E3P  3584

typedef __attribute__((ext_vector_type(8)))  __bf16 bf16x8;
typedef __attribute__((ext_vector_type(4)))  float  f32x4;
typedef __attribute__((ext_vector_type(16))) float  f32x16;
typedef __attribute__((ext_vector_type(4)))  unsigned int u32x4;

__device__ __forceinline__ short f2b(float x) {
  __hip_bfloat16 h = __float2bfloat16(x);
  return __builtin_bit_cast(short, h);
}
__device__ __forceinline__ float b2f(short x) {
  return __bfloat162float(__builtin_bit_cast(__hip_bfloat16, x));
}
__device__ __forceinline__ unsigned int pk2(float x, float y) {
  return (unsigned int)(unsigned short)f2b(x) |
         ((unsigned int)(unsigned short)f2b(y) << 16);
}
__device__ __forceinline__ void gload16(const void* g, void* l) {
  __builtin_amdgcn_global_load_lds(
      (const __attribute__((address_space(1))) unsigned int*)g,
      (__attribute__((address_space(3))) unsigned int*)l, 16, 0, 0);
}

#define BAR() __builtin_amdgcn_s_barrier()

// ---------------- fp32 -> bf16 convert ----------------
__global__ void k_cvt(const float* __restrict__ in, short* __restrict__ out, int n4) {
  int i = blockIdx.x * blockDim.x + threadIdx.x;
  int stride = gridDim.x * blockDim.x;
  for (; i < n4; i += stride) {
    float4 v = reinterpret_cast<const float4*>(in)[i];
    short4 o;
    o.x = f2b(v.x); o.y = f2b(v.y); o.z = f2b(v.z); o.w = f2b(v.w);
    reinterpret_cast<short4*>(out)[i] = o;
  }
}

// ---------------- 256x256 8-wave BK=64 4-phase pipelined GEMM: C = A*B^T + bias ----
// Phases: {ds_read frags | stage quarter-pair | BAR | setprio1 | 16 MFMA | setprio0 | BAR}
// NO inline lgkmcnt/sched_barrier: compiler-visible loads get auto-counted lgkmcnt,
// allowing ds_read/MFMA interleave (m141 lesson: sched_barrier(0) pinning is poison).
// Counted vmcnt(4) once per K-tile. Swizzle addr^=((addr>>7)&7)<<4, 0 conflicts.
template <int OUT_BF16>
__global__ __launch_bounds__(512, 2) void k_gemm256(
    const short* __restrict__ A, const short* __restrict__ B,
    const float* __restrict__ bias, void* __restrict__ Cout,
    int K, int Nreal)
{
  __shared__ __align__(16) short Als[2][4][64 * 64];
  __shared__ __align__(16) short Bls[2][4][64 * 64];
  const int t = threadIdx.x;
  const int lane = t & 63, wave = t >> 6;
  const int r16 = lane & 15, kg = lane >> 4;
  const int wm = wave >> 2, wn = wave & 3;
  const int m0 = blockIdx.x * 256, n0 = blockIdx.y * 256;
  const int NT = K >> 6;

  const int D = t * 16;
  const int L = D ^ (((D >> 7) & 7) << 4);
  const int srow = L >> 7, scol = (L & 127) >> 1;
  const short* pa = A + (size_t)(m0 + srow) * K + scol;
  const short* pb = B + (size_t)(n0 + srow) * K + scol;
  const int K64 = K * 64;

#define STAGE_A(bf, h, kt_) do { \
    gload16(pa + (h) * K64 + (kt_) * 64, (char*)Als[bf][h] + D); \
    gload16(pa + ((h) + 2) * K64 + (kt_) * 64, (char*)Als[bf][(h) + 2] + D); } while (0)
#define STAGE_B(bf, h, kt_) do { \
    gload16(pb + (h) * K64 + (kt_) * 64, (char*)Bls[bf][h] + D); \
    gload16(pb + ((h) + 2) * K64 + (kt_) * 64, (char*)Bls[bf][(h) + 2] + D); } while (0)

  const int cA0 = (kg * 16) ^ ((r16 & 7) << 4);
  const int cA1 = (64 + kg * 16) ^ ((r16 & 7) << 4);

  f32x4 acc[8][4] = {};

  // prologue: tile0 (all) + tile1 (X quarters) = 12 loads; wait oldest 8 (tile 0)
  STAGE_A(0, 0, 0); STAGE_B(0, 0, 0);
  STAGE_A(0, 1, 0); STAGE_B(0, 1, 0);
  STAGE_A(1, 0, 1); STAGE_B(1, 0, 1);
  asm volatile("s_waitcnt vmcnt(4)" ::: "memory");
  BAR();

  for (int kt = 0; kt < NT; ++kt) {
    const int bsel = kt & 1, bn1 = bsel ^ 1;
    const bool s1 = (kt + 1 < NT), s2 = (kt + 2 < NT);
    const char* aq0 = (const char*)Als[bsel][2 * wm];
    const char* aq1 = (const char*)Als[bsel][2 * wm + 1];
    const char* bq  = (const char*)Bls[bsel][wn];

    bf16x8 a_[2][2], b_[4][2];

    // ---- phase 0: A m0-1 + B all; stage AY(kt+1) ----
#pragma unroll
    for (int mi = 0; mi < 2; ++mi) {
      a_[mi][0] = *(const bf16x8*)(aq0 + (mi * 16 + r16) * 128 + cA0);
      a_[mi][1] = *(const bf16x8*)(aq0 + (mi * 16 + r16) * 128 + cA1);
    }
#pragma unroll
    for (int n = 0; n < 4; ++n) {
      b_[n][0] = *(const bf16x8*)(bq + (n * 16 + r16) * 128 + cA0);
      b_[n][1] = *(const bf16x8*)(bq + (n * 16 + r16) * 128 + cA1);
    }
    if (s1) STAGE_A(bn1, 1, kt + 1);
    BAR();
    __builtin_amdgcn_s_setprio(1);
#pragma unroll
    for (int mi = 0; mi < 2; ++mi)
#pragma unroll
      for (int n = 0; n < 4; ++n) {
        acc[mi][n] = __builtin_amdgcn_mfma_f32_16x16x32_bf16(a_[mi][0], b_[n][0], acc[mi][n], 0, 0, 0);
        acc[mi][n] = __builtin_amdgcn_mfma_f32_16x16x32_bf16(a_[mi][1], b_[n][1], acc[mi][n], 0, 0, 0);
      }
    __builtin_amdgcn_s_setprio(0);
    BAR();

    // ---- phase 1: A m2-3; stage BY(kt+1) ----
#pragma unroll
    for (int mi = 0; mi < 2; ++mi) {
      a_[mi][0] = *(const bf16x8*)(aq0 + ((mi + 2) * 16 + r16) * 128 + cA0);
      a_[mi][1] = *(const bf16x8*)(aq0 + ((mi + 2) * 16 + r16) * 128 + cA1);
    }
    if (s1) STAGE_B(bn1, 1, kt + 1);
    BAR();
    __builtin_amdgcn_s_setprio(1);
#pragma unroll
    for (int mi = 0; mi < 2; ++mi)
#pragma unroll
      for (int n = 0; n < 4; ++n) {
        acc[mi + 2][n] = __builtin_amdgcn_mfma_f32_16x16x32_bf16(a_[mi][0], b_[n][0], acc[mi + 2][n], 0, 0, 0);
        acc[mi + 2][n] = __builtin_amdgcn_mfma_f32_16x16x32_bf16(a_[mi][1], b_[n][1], acc[mi + 2][n], 0, 0, 0);
      }
    __builtin_amdgcn_s_setprio(0);
    BAR();

    // ---- phase 2: A m4-5; stage AX(kt+2) ----
#pragma unroll
    for (int mi = 0; mi < 2; ++mi) {
      a_[mi][0] = *(const bf16x8*)(aq1 + (mi * 16 + r16) * 128 + cA0);
      a_[mi][1] = *(const bf16x8*)(aq1 + (mi * 16 + r16) * 128 + cA1);
    }
    if (s2) STAGE_A(bsel, 0, kt + 2);
    BAR();
    __builtin_amdgcn_s_setprio(1);
#pragma unroll
    for (int mi = 0; mi < 2; ++mi)
#pragma unroll
      for (int n = 0; n < 4; ++n) {
        acc[mi + 4][n] = __builtin_amdgcn_mfma_f32_16x16x32_bf16(a_[mi][0], b_[n][0], acc[mi + 4][n], 0, 0, 0);
        acc[mi + 4][n] = __builtin_amdgcn_mfma_f32_16x16x32_bf16(a_[mi][1], b_[n][1], acc[mi + 4][n], 0, 0, 0);
      }
    __builtin_amdgcn_s_setprio(0);
    BAR();

    // ---- phase 3: A m6-7; stage BX(kt+2); counted vmcnt ----
#pragma unroll
    for (int mi = 0; mi < 2; ++mi) {
      a_[mi][0] = *(const bf16x8*)(aq1 + ((mi + 2) * 16 + r16) * 128 + cA0);
      a_[mi][1] = *(const bf16x8*)(aq1 + ((mi + 2) * 16 + r16) * 128 + cA1);
    }
    if (s2) STAGE_B(bsel, 0, kt + 2);
    BAR();
    __builtin_amdgcn_s_setprio(1);
#pragma unroll
    for (int mi = 0; mi < 2; ++mi)
#pragma unroll
      for (int n = 0; n < 4; ++n) {
        acc[mi + 6][n] = __builtin_amdgcn_mfma_f32_16x16x32_bf16(a_[mi][0], b_[n][0], acc[mi + 6][n], 0, 0, 0);
        acc[mi + 6][n] = __builtin_amdgcn_mfma_f32_16x16x32_bf16(a_[mi][1], b_[n][1], acc[mi + 6][n], 0, 0, 0);
      }
    __builtin_amdgcn_s_setprio(0);
    if (s2) { asm volatile("s_waitcnt vmcnt(4)" ::: "memory"); }
    else    { asm volatile("s_waitcnt vmcnt(0)" ::: "memory"); }
    BAR();
  }
#undef STAGE_A
#undef STAGE_B

  // epilogue
#pragma unroll
  for (int n = 0; n < 4; ++n) {
    int col = n0 + wn * 64 + n * 16 + r16;
    if (col < Nreal) {
      float bv = bias[col];
#pragma unroll
      for (int m = 0; m < 8; ++m)
#pragma unroll
        for (int r = 0; r < 4; ++r) {
          int row = m0 + wm * 128 + m * 16 + kg * 4 + r;
          float v = acc[m][n][r] + bv;
          if (OUT_BF16) ((short*)Cout)[(size_t)row * Nreal + col] = f2b(v);
          else          ((float*)Cout)[(size_t)row * Nreal + col] = v;
        }
    }
  }
}

// ---------------- 128x128 GEMM (proj), f32 out ----------------
__global__ __launch_bounds__(256) void k_gemm_bt_f32(
    const short* __restrict__ A, const short* __restrict__ B,
    const float* __restrict__ bias, float* __restrict__ Cout,
    int M, int N, int K)
{
  __shared__ __align__(16) short As[128 * 64];
  __shared__ __align__(16) short Bs[128 * 64];
  const int t = threadIdx.x;
  const int lane = t & 63, wave = t >> 6;
  const int r16 = lane & 15, kg = lane >> 4;
  const int m0 = blockIdx.x * 128, n0 = blockIdx.y * 128;
  const int wr = (wave >> 1) * 64, wc = (wave & 1) * 64;

  f32x4 acc[4][4] = {};

  for (int k0 = 0; k0 < K; k0 += 64) {
    __syncthreads();
#pragma unroll
    for (int i = 0; i < 4; ++i) {
      int c0 = wave * 64 + i * 256;
      int c = c0 + lane;
      int row = c >> 3, col = (c & 7) * 8;
      gload16(A + (m0 + row) * K + k0 + col, (char*)As + c0 * 16);
      gload16(B + (n0 + row) * K + k0 + col, (char*)Bs + c0 * 16);
    }
    __syncthreads();
#pragma unroll
    for (int kk = 0; kk < 2; ++kk) {
      bf16x8 a[4], b[4];
#pragma unroll
      for (int m = 0; m < 4; ++m)
        a[m] = *(const bf16x8*)&As[(wr + m * 16 + r16) * 64 + kk * 32 + kg * 8];
#pragma unroll
      for (int n = 0; n < 4; ++n)
        b[n] = *(const bf16x8*)&Bs[(wc + n * 16 + r16) * 64 + kk * 32 + kg * 8];
#pragma unroll
      for (int m = 0; m < 4; ++m)
#pragma unroll
        for (int n = 0; n < 4; ++n)
          acc[m][n] = __builtin_amdgcn_mfma_f32_16x16x32_bf16(a[m], b[n], acc[m][n], 0, 0, 0);
    }
  }

#pragma unroll
  for (int n = 0; n < 4; ++n) {
    int col = n0 + wc + n * 16 + r16;
    float bv = bias[col];
#pragma unroll
    for (int m = 0; m < 4; ++m) {
#pragma unroll
      for (int r = 0; r < 4; ++r) {
        int row = m0 + wr + m * 16 + kg * 4 + r;
        Cout[row * N + col] = acc[m][n][r] + bv;
      }
    }
  }
}

// ---------------- RoPE + Q/K/V repack ----------------
__global__ __launch_bounds__(256) void k_rope(
    const short* __restrict__ qkv, const float* __restrict__ cosb, const float* __restrict__ sinb,
    short* __restrict__ Qg, short* __restrict__ Kg, short* __restrict__ Vg)
{
  __shared__ short vt[72][64];
  const int b = blockIdx.x;
  const int seg = b >> 8, head = (b >> 4) & 15, pb = b & 15;
  const int pos0 = pb * 64;
  const int t = threadIdx.x;
  const int sh = seg * 16 + head;
  const float qscale = 0.17002540410995343f; // log2(e)/sqrt(72)

#pragma unroll
  for (int i = 0; i < 24; ++i) {
    int e = t + i * 256;
    int p = e / 96, d = e % 96;
    int s = seg * 1024 + pos0 + p;
    int ob = (sh * 1024 + pos0 + p) * 96 + d;
    short qo = 0, ko = 0;
    if (d < 72) {
      int base = s * E3 + head * 72;
      float c = cosb[s * 72 + d], sn = sinb[s * 72 + d];
      int d2 = d < 36 ? d + 36 : d - 36;
      float sgn = d < 36 ? -1.f : 1.f;
      float q1 = b2f(qkv[base + d]),        q2 = b2f(qkv[base + d2]);
      float k1 = b2f(qkv[base + 1152 + d]), k2 = b2f(qkv[base + 1152 + d2]);
      qo = f2b((q1 * c + sgn * q2 * sn) * qscale);
      ko = f2b(k1 * c + sgn * k2 * sn);
    }
    Qg[ob] = qo;
    Kg[ob] = ko;
  }
  for (int i = 0; i < 18; ++i) {
    int e = t + i * 256;
    int p = e / 72, d = e % 72;
    int s = seg * 1024 + pos0 + p;
    vt[d][p] = qkv[s * E3 + 2304 + head * 72 + d];
  }
  __syncthreads();
#pragma unroll
  for (int i = 0; i < 24; ++i) {
    int e = t + i * 256;
    int d = e >> 6, p = e & 63;
    short v;
    if (d < 72)       v = vt[d][p];
    else if (d == 72) v = (short)0x3F80;  // bf16 1.0 -> denominator column
    else              v = 0;
    Vg[(sh * 96 + d) * 1024 + pos0 + p] = v;
  }
}

// ---------------- Flash attention: swapped-QK 32x32, in-register softmax ----------------
#define KSS 104
#define VTS 72
__global__ __launch_bounds__(256, 3) void k_attn(
    const short* __restrict__ Qg, const short* __restrict__ Kg, const short* __restrict__ Vg,
    short* __restrict__ Og)
{
  __shared__ __align__(16) short Ks[64 * KSS];
  __shared__ __align__(16) short VT[96 * VTS];
  const int p_ = blockIdx.x;
  const int xcd = p_ & 7, rest = p_ >> 3;
  const int qb = rest & 7, shi = rest >> 3;
  const int sh = xcd * 16 + shi;
  const int seg = sh >> 4, head = sh & 15;
  const int t = threadIdx.x, lane = t & 63, wave = t >> 6;
  const int l31 = lane & 31, hi = lane >> 5;
  const int q0 = qb * 128 + wave * 32;

  // d=72..79 are zeros; dm=5 (d 80-95, also zeros) dropped: 5 MFMA pairs not 6
  bf16x8 qf[5];
  {
    const short* qp = Qg + ((size_t)(sh * 1024 + q0 + l31)) * 96 + hi * 8;
#pragma unroll
    for (int dm = 0; dm < 5; ++dm) qf[dm] = *(const bf16x8*)(qp + dm * 16);
  }

  const short* kbase = Kg + (size_t)sh * 1024 * 96;
  const short* vbase = Vg + (size_t)sh * 96 * 1024;
  int koff[4], voff[4];
#pragma unroll
  for (int i = 0; i < 4; ++i) {
    int c = t + i * 256;
    int kr = c / 13, kc8 = c - kr * 13;
    koff[i] = kr * 96 + ((kc8 == 12) ? 0 : kc8 * 8);
    int vr = c / 9, vc8 = c - vr * 9;
    voff[i] = vr * 1024 + ((vc8 == 8) ? 0 : vc8 * 8);
  }

  f32x16 acc0 = {}, acc1 = {}, acc2 = {};
  float Mrun = -1e30f;

  for (int kt = 0; kt < 16; ++kt) {
    __syncthreads();
    {
      const short* kp = kbase + kt * 64 * 96;
      const short* vp = vbase + kt * 64;
#pragma unroll
      for (int i = 0; i < 3; ++i) {
        gload16(kp + koff[i], (char*)Ks + (t + i * 256) * 16);
        gload16(vp + voff[i], (char*)VT + (t + i * 256) * 16);
      }
      if (t < 64) gload16(kp + koff[3], (char*)Ks + (t + 768) * 16);
      if (t < 96) gload16(vp + voff[3], (char*)VT + (t + 768) * 16);
    }
    __syncthreads();

    f32x16 s0 = {}, s1 = {};
#pragma unroll
    for (int dm = 0; dm < 5; ++dm) {
      bf16x8 kf0 = *(const bf16x8*)&Ks[l31 * KSS + dm * 16 + hi * 8];
      bf16x8 kf1 = *(const bf16x8*)&Ks[(32 + l31) * KSS + dm * 16 + hi * 8];
      s0 = __builtin_amdgcn_mfma_f32_32x32x16_bf16(kf0, qf[dm], s0, 0, 0, 0);
      s1 = __builtin_amdgcn_mfma_f32_32x32x16_bf16(kf1, qf[dm], s1, 0, 0, 0);
    }

    float pmax = s0[0];
#pragma unroll
    for (int r = 1; r < 16; ++r) pmax = fmaxf(pmax, s0[r]);
#pragma unroll
    for (int r = 0; r < 16; ++r) pmax = fmaxf(pmax, s1[r]);
    pmax = fmaxf(pmax, __shfl_xor(pmax, 32));

    if (__any(pmax > Mrun + 8.0f)) {
      float mn = fmaxf(Mrun, pmax);
      float corr = exp2f(Mrun - mn);
      Mrun = mn;
#pragma unroll
      for (int r = 0; r < 16; ++r) {
        int qr = (r & 3) + 8 * (r >> 2) + 4 * hi;
        float cr = __shfl(corr, qr);
        acc0[r] *= cr; acc1[r] *= cr; acc2[r] *= cr;
      }
    }

    unsigned int pk0[8], pk1[8];
#pragma unroll
    for (int b = 0; b < 4; ++b)
#pragma unroll
      for (int i = 0; i < 2; ++i) {
        pk0[b * 2 + i] = pk2(exp2f(s0[b * 4 + 2 * i] - Mrun), exp2f(s0[b * 4 + 2 * i + 1] - Mrun));
        pk1[b * 2 + i] = pk2(exp2f(s1[b * 4 + 2 * i] - Mrun), exp2f(s1[b * 4 + 2 * i + 1] - Mrun));
      }

#pragma unroll
    for (int ks = 0; ks < 4; ++ks) {
      const int k1 = ks & 1;
      unsigned int A0, A1, B0, B1;
      if (ks < 2) { A0 = pk0[4 * k1]; A1 = pk0[4 * k1 + 1]; B0 = pk0[4 * k1 + 2]; B1 = pk0[4 * k1 + 3]; }
      else        { A0 = pk1[4 * k1]; A1 = pk1[4 * k1 + 1]; B0 = pk1[4 * k1 + 2]; B1 = pk1[4 * k1 + 3]; }
      unsigned int SA0 = __shfl_xor((int)A0, 32), SA1 = __shfl_xor((int)A1, 32);
      unsigned int SB0 = __shfl_xor((int)B0, 32), SB1 = __shfl_xor((int)B1, 32);
      u32x4 wv;
      wv.x = hi ? SB0 : A0;
      wv.y = hi ? SB1 : A1;
      wv.z = hi ? B0 : SA0;
      wv.w = hi ? B1 : SA1;
      bf16x8 af = __builtin_bit_cast(bf16x8, wv);
      bf16x8 vf0 = *(const bf16x8*)&VT[l31 * VTS + ks * 16 + hi * 8];
      bf16x8 vf1 = *(const bf16x8*)&VT[(32 + l31) * VTS + ks * 16 + hi * 8];
      bf16x8 vf2 = *(const bf16x8*)&VT[(64 + l31) * VTS + ks * 16 + hi * 8];
      acc0 = __builtin_amdgcn_mfma_f32_32x32x16_bf16(af, vf0, acc0, 0, 0, 0);
      acc1 = __builtin_amdgcn_mfma_f32_32x32x16_bf16(af, vf1, acc1, 0, 0, 0);
      acc2 = __builtin_amdgcn_mfma_f32_32x32x16_bf16(af, vf2, acc2, 0, 0, 0);
    }
  }

#pragma unroll
  for (int r = 0; r < 16; ++r) {
    float l = __shfl(acc2[r], (lane & 32) | 8);
    float inv = 1.0f / l;
    int q = q0 + (r & 3) + 8 * (r >> 2) + 4 * hi;
    size_t base = (size_t)(seg * 1024 + q) * 1152 + head * 72;
    Og[base + l31]      = f2b(acc0[r] * inv);
    Og[base + 32 + l31] = f2b(acc1[r] * inv);
    if (l31 < 8) Og[base + 64 + l31] = f2b(acc2[r] * inv);
  }
}

// ---------------- launch ----------------
extern "C" void kernel_launch(void* const* d_in, const int* in_sizes, int n_in,
                              void* d_out, int out_size, void* d_ws, size_t ws_size,
                              hipStream_t stream) {
  (void)in_sizes; (void)n_in; (void)out_size; (void)ws_size;
  const float* x      = (const float*)d_in[0];
  const float* cosb   = (const float*)d_in[1];
  const float* sinb   = (const float*)d_in[2];
  const float* qkv_w  = (const float*)d_in[3];
  const float* qkv_b  = (const float*)d_in[4];
  const float* proj_w = (const float*)d_in[5];
  const float* proj_b = (const float*)d_in[6];

  char* ws = (char*)d_ws;
  size_t o = 0;
  short* xb  = (short*)(ws + o); o += (size_t)SS * EE * 2;
  short* qwb = (short*)(ws + o); o += (size_t)E3P * EE * 2;
  short* pwb = (short*)(ws + o); o += (size_t)EE * EE * 2;
  short* qkv = (short*)(ws + o); o += (size_t)SS * E3 * 2;
  short* Qg  = (short*)(ws + o); o += (size_t)SEGN * HH * LSEG * DP * 2;
  short* Kg  = (short*)(ws + o); o += (size_t)SEGN * HH * LSEG * DP * 2;
  short* Vg  = (short*)(ws + o); o += (size_t)SEGN * HH * DP * LSEG * 2;
  short* og  = xb; // x dead after GEMM1

  k_cvt<<<2048, 256, 0, stream>>>(x, xb, SS * EE / 4);
  k_cvt<<<1024, 256, 0, stream>>>(qkv_w, qwb, E3 * EE / 4);
  k_cvt<<<512, 256, 0, stream>>>(proj_w, pwb, EE * EE / 4);

  dim3 g1(SS / 256, E3P / 256);   // 32 x 14 = 448 blocks
  k_gemm256<1><<<g1, 512, 0, stream>>>(xb, qwb, qkv_b, qkv, EE, E3);

  k_rope<<<SEGN * HH * 16, 256, 0, stream>>>(qkv, cosb, sinb, Qg, Kg, Vg);

  k_attn<<<SEGN * HH * 8, 256, 0, stream>>>(Qg, Kg, Vg, og);

  dim3 g2(SS / 128, EE / 128);    // 64 x 9 = 576 blocks
  k_gemm_bt_f32<<<g2, 256, 0, stream>>>(og, pwb, proj_b, (float*)d_out, SS, EE, EE);
}

// Round 7
// 264.838 us; speedup vs baseline: 1.0581x; 1.0581x over previous
//
#include <hip/hip_runtime.h>
#include <hip/hip_bf16.h>
#include <stdint.h>

#define SEGN 8
#define LSEG 1024
#define SS   8192
#define EE   1152
#define HH   16
#define DD   72
#define DP   96
#define E3   3456
#define E3P  3584
#define EEP  1280

typedef __attribute__((ext_vector_type(8)))  __bf16 bf16x8;
typedef __attribute__((ext_vector_type(4)))  float  f32x4;
typedef __attribute__((ext_vector_type(16))) float  f32x16;
typedef __attribute__((ext_vector_type(4)))  unsigned int u32x4;

__device__ __forceinline__ short f2b(float x) {
  __hip_bfloat16 h = __float2bfloat16(x);
  return __builtin_bit_cast(short, h);
}
__device__ __forceinline__ float b2f(short x) {
  return __bfloat162float(__builtin_bit_cast(__hip_bfloat16, x));
}
__device__ __forceinline__ unsigned int pk2(float x, float y) {
  return (unsigned int)(unsigned short)f2b(x) |
         ((unsigned int)(unsigned short)f2b(y) << 16);
}
__device__ __forceinline__ void gload16(const void* g, void* l) {
  __builtin_amdgcn_global_load_lds(
      (const __attribute__((address_space(1))) unsigned int*)g,
      (__attribute__((address_space(3))) unsigned int*)l, 16, 0, 0);
}

#define BAR() __builtin_amdgcn_s_barrier()

// ---------------- fp32 -> bf16 convert ----------------
__global__ void k_cvt(const float* __restrict__ in, short* __restrict__ out, int n4) {
  int i = blockIdx.x * blockDim.x + threadIdx.x;
  int stride = gridDim.x * blockDim.x;
  for (; i < n4; i += stride) {
    float4 v = reinterpret_cast<const float4*>(in)[i];
    short4 o;
    o.x = f2b(v.x); o.y = f2b(v.y); o.z = f2b(v.z); o.w = f2b(v.w);
    reinterpret_cast<short4*>(out)[i] = o;
  }
}

// ---------------- 256x256 8-wave BK=64 4-phase pipelined GEMM: C = A*B^T + bias ----
template <int OUT_BF16>
__global__ __launch_bounds__(512, 2) void k_gemm256(
    const short* __restrict__ A, const short* __restrict__ B,
    const float* __restrict__ bias, void* __restrict__ Cout,
    int K, int Nreal)
{
  __shared__ __align__(16) short Als[2][4][64 * 64];
  __shared__ __align__(16) short Bls[2][4][64 * 64];
  const int t = threadIdx.x;
  const int lane = t & 63, wave = t >> 6;
  const int r16 = lane & 15, kg = lane >> 4;
  const int wm = wave >> 2, wn = wave & 3;
  const int m0 = blockIdx.x * 256, n0 = blockIdx.y * 256;
  const int NT = K >> 6;

  const int D = t * 16;
  const int L = D ^ (((D >> 7) & 7) << 4);
  const int srow = L >> 7, scol = (L & 127) >> 1;
  const short* pa = A + (size_t)(m0 + srow) * K + scol;
  const short* pb = B + (size_t)(n0 + srow) * K + scol;
  const int K64 = K * 64;

#define STAGE_A(bf, h, kt_) do { \
    gload16(pa + (h) * K64 + (kt_) * 64, (char*)Als[bf][h] + D); \
    gload16(pa + ((h) + 2) * K64 + (kt_) * 64, (char*)Als[bf][(h) + 2] + D); } while (0)
#define STAGE_B(bf, h, kt_) do { \
    gload16(pb + (h) * K64 + (kt_) * 64, (char*)Bls[bf][h] + D); \
    gload16(pb + ((h) + 2) * K64 + (kt_) * 64, (char*)Bls[bf][(h) + 2] + D); } while (0)

  const int cA0 = (kg * 16) ^ ((r16 & 7) << 4);
  const int cA1 = (64 + kg * 16) ^ ((r16 & 7) << 4);

  f32x4 acc[8][4] = {};

  STAGE_A(0, 0, 0); STAGE_B(0, 0, 0);
  STAGE_A(0, 1, 0); STAGE_B(0, 1, 0);
  STAGE_A(1, 0, 1); STAGE_B(1, 0, 1);
  asm volatile("s_waitcnt vmcnt(4)" ::: "memory");
  BAR();

  for (int kt = 0; kt < NT; ++kt) {
    const int bsel = kt & 1, bn1 = bsel ^ 1;
    const bool s1 = (kt + 1 < NT), s2 = (kt + 2 < NT);
    const char* aq0 = (const char*)Als[bsel][2 * wm];
    const char* aq1 = (const char*)Als[bsel][2 * wm + 1];
    const char* bq  = (const char*)Bls[bsel][wn];

    bf16x8 a_[2][2], b_[4][2];

    // ---- phase 0: A m0-1 + B all; stage AY(kt+1) ----
#pragma unroll
    for (int mi = 0; mi < 2; ++mi) {
      a_[mi][0] = *(const bf16x8*)(aq0 + (mi * 16 + r16) * 128 + cA0);
      a_[mi][1] = *(const bf16x8*)(aq0 + (mi * 16 + r16) * 128 + cA1);
    }
#pragma unroll
    for (int n = 0; n < 4; ++n) {
      b_[n][0] = *(const bf16x8*)(bq + (n * 16 + r16) * 128 + cA0);
      b_[n][1] = *(const bf16x8*)(bq + (n * 16 + r16) * 128 + cA1);
    }
    if (s1) STAGE_A(bn1, 1, kt + 1);
    BAR();
    __builtin_amdgcn_s_setprio(1);
#pragma unroll
    for (int mi = 0; mi < 2; ++mi)
#pragma unroll
      for (int n = 0; n < 4; ++n) {
        acc[mi][n] = __builtin_amdgcn_mfma_f32_16x16x32_bf16(a_[mi][0], b_[n][0], acc[mi][n], 0, 0, 0);
        acc[mi][n] = __builtin_amdgcn_mfma_f32_16x16x32_bf16(a_[mi][1], b_[n][1], acc[mi][n], 0, 0, 0);
      }
    __builtin_amdgcn_s_setprio(0);
    BAR();

    // ---- phase 1: A m2-3; stage BY(kt+1) ----
#pragma unroll
    for (int mi = 0; mi < 2; ++mi) {
      a_[mi][0] = *(const bf16x8*)(aq0 + ((mi + 2) * 16 + r16) * 128 + cA0);
      a_[mi][1] = *(const bf16x8*)(aq0 + ((mi + 2) * 16 + r16) * 128 + cA1);
    }
    if (s1) STAGE_B(bn1, 1, kt + 1);
    BAR();
    __builtin_amdgcn_s_setprio(1);
#pragma unroll
    for (int mi = 0; mi < 2; ++mi)
#pragma unroll
      for (int n = 0; n < 4; ++n) {
        acc[mi + 2][n] = __builtin_amdgcn_mfma_f32_16x16x32_bf16(a_[mi][0], b_[n][0], acc[mi + 2][n], 0, 0, 0);
        acc[mi + 2][n] = __builtin_amdgcn_mfma_f32_16x16x32_bf16(a_[mi][1], b_[n][1], acc[mi + 2][n], 0, 0, 0);
      }
    __builtin_amdgcn_s_setprio(0);
    BAR();

    // ---- phase 2: A m4-5; stage AX(kt+2) ----
#pragma unroll
    for (int mi = 0; mi < 2; ++mi) {
      a_[mi][0] = *(const bf16x8*)(aq1 + (mi * 16 + r16) * 128 + cA0);
      a_[mi][1] = *(const bf16x8*)(aq1 + (mi * 16 + r16) * 128 + cA1);
    }
    if (s2) STAGE_A(bsel, 0, kt + 2);
    BAR();
    __builtin_amdgcn_s_setprio(1);
#pragma unroll
    for (int mi = 0; mi < 2; ++mi)
#pragma unroll
      for (int n = 0; n < 4; ++n) {
        acc[mi + 4][n] = __builtin_amdgcn_mfma_f32_16x16x32_bf16(a_[mi][0], b_[n][0], acc[mi + 4][n], 0, 0, 0);
        acc[mi + 4][n] = __builtin_amdgcn_mfma_f32_16x16x32_bf16(a_[mi][1], b_[n][1], acc[mi + 4][n], 0, 0, 0);
      }
    __builtin_amdgcn_s_setprio(0);
    BAR();

    // ---- phase 3: A m6-7; stage BX(kt+2); counted vmcnt ----
#pragma unroll
    for (int mi = 0; mi < 2; ++mi) {
      a_[mi][0] = *(const bf16x8*)(aq1 + ((mi + 2) * 16 + r16) * 128 + cA0);
      a_[mi][1] = *(const bf16x8*)(aq1 + ((mi + 2) * 16 + r16) * 128 + cA1);
    }
    if (s2) STAGE_B(bsel, 0, kt + 2);
    BAR();
    __builtin_amdgcn_s_setprio(1);
#pragma unroll
    for (int mi = 0; mi < 2; ++mi)
#pragma unroll
      for (int n = 0; n < 4; ++n) {
        acc[mi + 6][n] = __builtin_amdgcn_mfma_f32_16x16x32_bf16(a_[mi][0], b_[n][0], acc[mi + 6][n], 0, 0, 0);
        acc[mi + 6][n] = __builtin_amdgcn_mfma_f32_16x16x32_bf16(a_[mi][1], b_[n][1], acc[mi + 6][n], 0, 0, 0);
      }
    __builtin_amdgcn_s_setprio(0);
    if (s2) { asm volatile("s_waitcnt vmcnt(4)" ::: "memory"); }
    else    { asm volatile("s_waitcnt vmcnt(0)" ::: "memory"); }
    BAR();
  }
#undef STAGE_A
#undef STAGE_B

#pragma unroll
  for (int n = 0; n < 4; ++n) {
    int col = n0 + wn * 64 + n * 16 + r16;
    if (col < Nreal) {
      float bv = bias[col];
#pragma unroll
      for (int m = 0; m < 8; ++m)
#pragma unroll
        for (int r = 0; r < 4; ++r) {
          int row = m0 + wm * 128 + m * 16 + kg * 4 + r;
          float v = acc[m][n][r] + bv;
          if (OUT_BF16) ((short*)Cout)[(size_t)row * Nreal + col] = f2b(v);
          else          ((float*)Cout)[(size_t)row * Nreal + col] = v;
        }
    }
  }
}

// ---------------- RoPE + Q/K/V repack ----------------
__global__ __launch_bounds__(256) void k_rope(
    const short* __restrict__ qkv, const float* __restrict__ cosb, const float* __restrict__ sinb,
    short* __restrict__ Qg, short* __restrict__ Kg, short* __restrict__ Vg)
{
  __shared__ short vt[72][64];
  const int b = blockIdx.x;
  const int seg = b >> 8, head = (b >> 4) & 15, pb = b & 15;
  const int pos0 = pb * 64;
  const int t = threadIdx.x;
  const int sh = seg * 16 + head;
  const float qscale = 0.17002540410995343f; // log2(e)/sqrt(72)

#pragma unroll
  for (int i = 0; i < 24; ++i) {
    int e = t + i * 256;
    int p = e / 96, d = e % 96;
    int s = seg * 1024 + pos0 + p;
    int ob = (sh * 1024 + pos0 + p) * 96 + d;
    short qo = 0, ko = 0;
    if (d < 72) {
      int base = s * E3 + head * 72;
      float c = cosb[s * 72 + d], sn = sinb[s * 72 + d];
      int d2 = d < 36 ? d + 36 : d - 36;
      float sgn = d < 36 ? -1.f : 1.f;
      float q1 = b2f(qkv[base + d]),        q2 = b2f(qkv[base + d2]);
      float k1 = b2f(qkv[base + 1152 + d]), k2 = b2f(qkv[base + 1152 + d2]);
      qo = f2b((q1 * c + sgn * q2 * sn) * qscale);
      ko = f2b(k1 * c + sgn * k2 * sn);
    }
    Qg[ob] = qo;
    Kg[ob] = ko;
  }
  for (int i = 0; i < 18; ++i) {
    int e = t + i * 256;
    int p = e / 72, d = e % 72;
    int s = seg * 1024 + pos0 + p;
    vt[d][p] = qkv[s * E3 + 2304 + head * 72 + d];
  }
  __syncthreads();
#pragma unroll
  for (int i = 0; i < 24; ++i) {
    int e = t + i * 256;
    int d = e >> 6, p = e & 63;
    short v;
    if (d < 72)       v = vt[d][p];
    else if (d == 72) v = (short)0x3F80;  // bf16 1.0 -> denominator column
    else              v = 0;
    Vg[(sh * 96 + d) * 1024 + pos0 + p] = v;
  }
}

// ---------------- Flash attention: swapped-QK 32x32, double-buffered async staging ----
// T3 minimal 2-phase: STAGE(buf^1, t+1) issued BEFORE compute(buf, t); one
// __syncthreads() per tile (its vmcnt/lgkm drain is the required wait).
#define KSS 104
#define VTS 72
__global__ __launch_bounds__(256, 2) void k_attn(
    const short* __restrict__ Qg, const short* __restrict__ Kg, const short* __restrict__ Vg,
    short* __restrict__ Og)
{
  __shared__ __align__(16) short Ks[2][64 * KSS];
  __shared__ __align__(16) short VT[2][96 * VTS];
  const int p_ = blockIdx.x;
  const int xcd = p_ & 7, rest = p_ >> 3;
  const int qb = rest & 7, shi = rest >> 3;
  const int sh = xcd * 16 + shi;
  const int seg = sh >> 4, head = sh & 15;
  const int t = threadIdx.x, lane = t & 63, wave = t >> 6;
  const int l31 = lane & 31, hi = lane >> 5;
  const int q0 = qb * 128 + wave * 32;

  bf16x8 qf[5];
  {
    const short* qp = Qg + ((size_t)(sh * 1024 + q0 + l31)) * 96 + hi * 8;
#pragma unroll
    for (int dm = 0; dm < 5; ++dm) qf[dm] = *(const bf16x8*)(qp + dm * 16);
  }

  const short* kbase = Kg + (size_t)sh * 1024 * 96;
  const short* vbase = Vg + (size_t)sh * 96 * 1024;
  int koff[4], voff[4];
#pragma unroll
  for (int i = 0; i < 4; ++i) {
    int c = t + i * 256;
    int kr = c / 13, kc8 = c - kr * 13;
    koff[i] = kr * 96 + ((kc8 == 12) ? 0 : kc8 * 8);
    int vr = c / 9, vc8 = c - vr * 9;
    voff[i] = vr * 1024 + ((vc8 == 8) ? 0 : vc8 * 8);
  }

  f32x16 acc0 = {}, acc1 = {}, acc2 = {};
  float Mrun = -1e30f;

  // prologue: stage tile 0 into buffer 0
  {
    const short* kp = kbase;
    const short* vp = vbase;
#pragma unroll
    for (int i = 0; i < 3; ++i) {
      gload16(kp + koff[i], (char*)Ks[0] + (t + i * 256) * 16);
      gload16(vp + voff[i], (char*)VT[0] + (t + i * 256) * 16);
    }
    if (t < 64) gload16(kp + koff[3], (char*)Ks[0] + (t + 768) * 16);
    if (t < 96) gload16(vp + voff[3], (char*)VT[0] + (t + 768) * 16);
  }
  __syncthreads();

  for (int kt = 0; kt < 16; ++kt) {
    const int cur = kt & 1;
    // issue next tile's staging into the other buffer (latency hides under compute)
    if (kt < 15) {
      const int nb = cur ^ 1;
      const short* kp = kbase + (kt + 1) * 64 * 96;
      const short* vp = vbase + (kt + 1) * 64;
#pragma unroll
      for (int i = 0; i < 3; ++i) {
        gload16(kp + koff[i], (char*)Ks[nb] + (t + i * 256) * 16);
        gload16(vp + voff[i], (char*)VT[nb] + (t + i * 256) * 16);
      }
      if (t < 64) gload16(kp + koff[3], (char*)Ks[nb] + (t + 768) * 16);
      if (t < 96) gload16(vp + voff[3], (char*)VT[nb] + (t + 768) * 16);
    }

    // QK^T swapped
    f32x16 s0 = {}, s1 = {};
    __builtin_amdgcn_s_setprio(1);
#pragma unroll
    for (int dm = 0; dm < 5; ++dm) {
      bf16x8 kf0 = *(const bf16x8*)&Ks[cur][l31 * KSS + dm * 16 + hi * 8];
      bf16x8 kf1 = *(const bf16x8*)&Ks[cur][(32 + l31) * KSS + dm * 16 + hi * 8];
      s0 = __builtin_amdgcn_mfma_f32_32x32x16_bf16(kf0, qf[dm], s0, 0, 0, 0);
      s1 = __builtin_amdgcn_mfma_f32_32x32x16_bf16(kf1, qf[dm], s1, 0, 0, 0);
    }
    __builtin_amdgcn_s_setprio(0);

    float pmax = s0[0];
#pragma unroll
    for (int r = 1; r < 16; ++r) pmax = fmaxf(pmax, s0[r]);
#pragma unroll
    for (int r = 0; r < 16; ++r) pmax = fmaxf(pmax, s1[r]);
    pmax = fmaxf(pmax, __shfl_xor(pmax, 32));

    if (__any(pmax > Mrun + 8.0f)) {
      float mn = fmaxf(Mrun, pmax);
      float corr = exp2f(Mrun - mn);
      Mrun = mn;
#pragma unroll
      for (int r = 0; r < 16; ++r) {
        int qr = (r & 3) + 8 * (r >> 2) + 4 * hi;
        float cr = __shfl(corr, qr);
        acc0[r] *= cr; acc1[r] *= cr; acc2[r] *= cr;
      }
    }

    unsigned int pk0[8], pk1[8];
#pragma unroll
    for (int b = 0; b < 4; ++b)
#pragma unroll
      for (int i = 0; i < 2; ++i) {
        pk0[b * 2 + i] = pk2(exp2f(s0[b * 4 + 2 * i] - Mrun), exp2f(s0[b * 4 + 2 * i + 1] - Mrun));
        pk1[b * 2 + i] = pk2(exp2f(s1[b * 4 + 2 * i] - Mrun), exp2f(s1[b * 4 + 2 * i + 1] - Mrun));
      }

    __builtin_amdgcn_s_setprio(1);
#pragma unroll
    for (int ks = 0; ks < 4; ++ks) {
      const int k1 = ks & 1;
      unsigned int A0, A1, B0, B1;
      if (ks < 2) { A0 = pk0[4 * k1]; A1 = pk0[4 * k1 + 1]; B0 = pk0[4 * k1 + 2]; B1 = pk0[4 * k1 + 3]; }
      else        { A0 = pk1[4 * k1]; A1 = pk1[4 * k1 + 1]; B0 = pk1[4 * k1 + 2]; B1 = pk1[4 * k1 + 3]; }
      unsigned int SA0 = __shfl_xor((int)A0, 32), SA1 = __shfl_xor((int)A1, 32);
      unsigned int SB0 = __shfl_xor((int)B0, 32), SB1 = __shfl_xor((int)B1, 32);
      u32x4 wv;
      wv.x = hi ? SB0 : A0;
      wv.y = hi ? SB1 : A1;
      wv.z = hi ? B0 : SA0;
      wv.w = hi ? B1 : SA1;
      bf16x8 af = __builtin_bit_cast(bf16x8, wv);
      bf16x8 vf0 = *(const bf16x8*)&VT[cur][l31 * VTS + ks * 16 + hi * 8];
      bf16x8 vf1 = *(const bf16x8*)&VT[cur][(32 + l31) * VTS + ks * 16 + hi * 8];
      bf16x8 vf2 = *(const bf16x8*)&VT[cur][(64 + l31) * VTS + ks * 16 + hi * 8];
      acc0 = __builtin_amdgcn_mfma_f32_32x32x16_bf16(af, vf0, acc0, 0, 0, 0);
      acc1 = __builtin_amdgcn_mfma_f32_32x32x16_bf16(af, vf1, acc1, 0, 0, 0);
      acc2 = __builtin_amdgcn_mfma_f32_32x32x16_bf16(af, vf2, acc2, 0, 0, 0);
    }
    __builtin_amdgcn_s_setprio(0);

    __syncthreads();  // drains vmcnt (next tile staged) + all reads of cur done
  }

#pragma unroll
  for (int r = 0; r < 16; ++r) {
    float l = __shfl(acc2[r], (lane & 32) | 8);
    float inv = 1.0f / l;
    int q = q0 + (r & 3) + 8 * (r >> 2) + 4 * hi;
    size_t base = (size_t)(seg * 1024 + q) * 1152 + head * 72;
    Og[base + l31]      = f2b(acc0[r] * inv);
    Og[base + 32 + l31] = f2b(acc1[r] * inv);
    if (l31 < 8) Og[base + 64 + l31] = f2b(acc2[r] * inv);
  }
}

// ---------------- launch ----------------
extern "C" void kernel_launch(void* const* d_in, const int* in_sizes, int n_in,
                              void* d_out, int out_size, void* d_ws, size_t ws_size,
                              hipStream_t stream) {
  (void)in_sizes; (void)n_in; (void)out_size; (void)ws_size;
  const float* x      = (const float*)d_in[0];
  const float* cosb   = (const float*)d_in[1];
  const float* sinb   = (const float*)d_in[2];
  const float* qkv_w  = (const float*)d_in[3];
  const float* qkv_b  = (const float*)d_in[4];
  const float* proj_w = (const float*)d_in[5];
  const float* proj_b = (const float*)d_in[6];

  char* ws = (char*)d_ws;
  size_t o = 0;
  short* xb  = (short*)(ws + o); o += (size_t)SS * EE * 2;
  short* qwb = (short*)(ws + o); o += (size_t)E3P * EE * 2;
  short* pwb = (short*)(ws + o); o += (size_t)EEP * EE * 2;
  short* qkv = (short*)(ws + o); o += (size_t)SS * E3 * 2;
  short* Qg  = (short*)(ws + o); o += (size_t)SEGN * HH * LSEG * DP * 2;
  short* Kg  = (short*)(ws + o); o += (size_t)SEGN * HH * LSEG * DP * 2;
  short* Vg  = (short*)(ws + o); o += (size_t)SEGN * HH * DP * LSEG * 2;
  short* og  = xb; // x dead after GEMM1

  k_cvt<<<2048, 256, 0, stream>>>(x, xb, SS * EE / 4);
  k_cvt<<<1024, 256, 0, stream>>>(qkv_w, qwb, E3 * EE / 4);
  k_cvt<<<512, 256, 0, stream>>>(proj_w, pwb, EE * EE / 4);

  dim3 g1(SS / 256, E3P / 256);   // 32 x 14 = 448 blocks
  k_gemm256<1><<<g1, 512, 0, stream>>>(xb, qwb, qkv_b, qkv, EE, E3);

  k_rope<<<SEGN * HH * 16, 256, 0, stream>>>(qkv, cosb, sinb, Qg, Kg, Vg);

  k_attn<<<SEGN * HH * 8, 256, 0, stream>>>(Qg, Kg, Vg, og);

  dim3 g2(SS / 256, EEP / 256);   // 32 x 5 = 160 blocks
  k_gemm256<0><<<g2, 512, 0, stream>>>(og, pwb, proj_b, d_out, EE, EE);
}